// Round 19
// baseline (57.113 us; speedup 1.0000x reference)
//
#include <hip/hip_runtime.h>
#include <hip/hip_bf16.h>
#include <math.h>

// Problem dims
#define BB 2
#define LL 2048
#define DD 768
#define D3 2304
#define HH 12
#define EE 32
#define RR 57
#define NN 20
#define PP 248
#define MM 256
#define KS 8
#define KCH (LL / KS)   // 256
#define R80 80
#define NSL 40          // score k-slices: 4 es + 4 eo + 32 c

// ws layout (float offsets)
#define ENT_EMB_OFF 0                           // f32 [B][EE][DD]
#define A16_OFF   (BB * EE * DD)                // bf16 [B][MM][LL]
#define A16_F     (BB * MM * LL / 2)
#define CPART_OFF (A16_OFF + A16_F)             // bf16 [KS][B][MM][DD]
#define CPART_F   (KS * BB * MM * DD / 2)
#define CODE16_OFF (CPART_OFF + CPART_F)        // bf16 [80][2304]
#define CODE16_F  (R80 * D3 / 2)
#define QSUM_OFF  (CODE16_OFF + CODE16_F)       // f32 [512] (1/qsum)
#define SACC_OFF  (QSUM_OFF + 512)              // f32 [512][NN] (nota sums)

// kP grid roles
#define NQBLK (BB * 256)          // att gather
#define NEBLK (EE * BB)           // ent_emb
#define NCBLK 8                   // code cast
#define NZBLK 4                   // zero out + sacc
#define ASTRIDE 388

// k3 grid roles
#define NGBLK 768
#define NQSB 16

#define OUT_F (BB * PP * (RR + 1))   // 28768 floats

typedef __attribute__((ext_vector_type(8))) short bf16x8;
typedef __attribute__((ext_vector_type(4))) float f32x4;

__device__ __forceinline__ unsigned short f2bf(float f) {
    __hip_bfloat16 h = __float2bfloat16(f);
    return __builtin_bit_cast(unsigned short, h);
}
__device__ __forceinline__ float bf2f(unsigned short u) {
    unsigned int x = ((unsigned int)u) << 16;
    return __builtin_bit_cast(float, x);
}
__device__ __forceinline__ void pair_so(int p, int& s, int& o) {
    s = p / 31;
    int r = p - s * 31;
    o = (r < s) ? r : r + 1;
}
__device__ __forceinline__ float dot4(float4 a, float4 b) {
    return a.x * b.x + a.y * b.y + a.z * b.z + a.w * b.w;
}
__device__ __forceinline__ void cast8(float4 u0, float4 u1, short* dst) {
    ushort4 a = make_ushort4(f2bf(u0.x), f2bf(u0.y), f2bf(u0.z), f2bf(u0.w));
    ushort4 b = make_ushort4(f2bf(u1.x), f2bf(u1.y), f2bf(u1.z), f2bf(u1.w));
    *(ushort4*)dst = a;
    *(ushort4*)(dst + 4) = b;
}

// ===== Kernel P: role Q (att gather, r16-proven), role E, role C, role Z (zero) =====
__global__ __launch_bounds__(256) void kP(const float* __restrict__ seq,
                                          const float* __restrict__ att,
                                          const float* __restrict__ rel,
                                          const float* __restrict__ nota,
                                          const int* __restrict__ spans,
                                          float* __restrict__ ws,
                                          float* __restrict__ out) {
    __shared__ __align__(16) float att_s[8][ASTRIDE];
    __shared__ int sp_s[EE];
    int bid = blockIdx.x;
    int t = threadIdx.x;

    if (bid < NQBLK) {
        int xcd = bid & 7, i = bid >> 3;
        int chunk = xcd * (NQBLK / 8) + i;       // 0..511
        int b = chunk >> 8, l0 = (chunk & 255) * 8;
        if (t < EE) sp_s[t] = spans[b * EE + t];
        __syncthreads();
        for (int i2 = t; i2 < EE * HH * 2; i2 += 256) {
            int seg = i2 & 1, eh = i2 >> 1;
            int e = eh / HH, h = eh - e * HH;
            const float* base = att + ((size_t)(b * HH + h) * LL + sp_s[e]) * LL + l0 + seg * 4;
            float4 v0 = *(const float4*)base;
            float4 v1 = *(const float4*)(base + LL);
            float4 v2 = *(const float4*)(base + 2 * LL);
            float4 v3 = *(const float4*)(base + 3 * LL);
            att_s[seg * 4 + 0][eh] = 0.25f * (v0.x + v1.x + v2.x + v3.x);
            att_s[seg * 4 + 1][eh] = 0.25f * (v0.y + v1.y + v2.y + v3.y);
            att_s[seg * 4 + 2][eh] = 0.25f * (v0.z + v1.z + v2.z + v3.z);
            att_s[seg * 4 + 3][eh] = 0.25f * (v0.w + v1.w + v2.w + v3.w);
        }
        __syncthreads();
        int p = t, s, o;
        pair_so(p, s, o);          // pads p>=248 -> s=8, o<=7: valid indices
        float q[8];
        #pragma unroll
        for (int l = 0; l < 8; ++l) {
            float4 a0 = *(const float4*)&att_s[l][s * HH];
            float4 a1 = *(const float4*)&att_s[l][s * HH + 4];
            float4 a2 = *(const float4*)&att_s[l][s * HH + 8];
            float4 b0 = *(const float4*)&att_s[l][o * HH];
            float4 b1 = *(const float4*)&att_s[l][o * HH + 4];
            float4 b2 = *(const float4*)&att_s[l][o * HH + 8];
            q[l] = dot4(a0, b0) + dot4(a1, b1) + dot4(a2, b2);
        }
        unsigned short* A16 = (unsigned short*)(ws + A16_OFF) + (size_t)(b * MM + p) * LL + l0;
        #pragma unroll
        for (int i2 = 0; i2 < 2; ++i2) {
            ushort4 ov = make_ushort4(f2bf(q[i2 * 4 + 0]), f2bf(q[i2 * 4 + 1]),
                                      f2bf(q[i2 * 4 + 2]), f2bf(q[i2 * 4 + 3]));
            *(ushort4*)(A16 + i2 * 4) = ov;
        }
    } else if (bid < NQBLK + NEBLK) {
        int bx = bid - NQBLK;
        int e = bx & 31, b = bx >> 5;
        int st = spans[b * EE + e];
        float* ee = ws + ENT_EMB_OFF + (size_t)(b * EE + e) * DD;
        const float* srow = seq + (size_t)(b * LL + st) * DD;
        for (int d = t; d < DD; d += 256) {
            ee[d] = 0.25f * (srow[d] + srow[DD + d] + srow[2 * DD + d] + srow[3 * DD + d]);
        }
    } else if (bid < NQBLK + NEBLK + NCBLK) {
        int cid = bid - NQBLK - NEBLK;
        unsigned short* code16 = (unsigned short*)(ws + CODE16_OFF);
        for (int idx = t; idx < 10 * (D3 / 4); idx += 256) {
            int rl = idx / (D3 / 4), dg = idx - rl * (D3 / 4);
            int r = cid * 10 + rl;
            ushort4 ov;
            if (r < RR) {
                float4 v = *(const float4*)(rel + (size_t)r * D3 + dg * 4);
                ov = make_ushort4(f2bf(v.x), f2bf(v.y), f2bf(v.z), f2bf(v.w));
            } else if (r < RR + NN) {
                float4 v = *(const float4*)(nota + (size_t)(r - RR) * D3 + dg * 4);
                ov = make_ushort4(f2bf(v.x), f2bf(v.y), f2bf(v.z), f2bf(v.w));
            } else {
                ov = make_ushort4(0, 0, 0, 0);
            }
            *(ushort4*)(code16 + (size_t)r * D3 + dg * 4) = ov;
        }
    } else {
        // role Z: zero out (accumulated by k4b atomics) + sacc
        int zid = bid - NQBLK - NEBLK - NCBLK;   // 0..3
        int per_out = (OUT_F + NZBLK - 1) / NZBLK;
        for (int i = zid * per_out + t; i < min((zid + 1) * per_out, OUT_F); i += 256)
            out[i] = 0.f;
        int per_sa = (512 * NN + NZBLK - 1) / NZBLK;
        for (int i = zid * per_sa + t; i < min((zid + 1) * per_sa, 512 * NN); i += 256)
            ws[SACC_OFF + i] = 0.f;
    }
}

// ===== Kernel 3: [0,768) register-direct context GEMM; [768,784) qsum =====
__global__ __launch_bounds__(256) void k3_gemm(const float* __restrict__ seq,
                                               float* __restrict__ ws) {
    int g = blockIdx.x;
    int t = threadIdx.x;
    int w = t >> 6, lane = t & 63;

    if (g < NGBLK) {
        int m0 = (g & 3) * 64;
        int n0 = ((g >> 2) % 12) * 64;
        int z = g / 48;
        int ks = z & 7, b = z >> 3;
        const unsigned short* A = (const unsigned short*)(ws + A16_OFF) + (size_t)b * MM * LL;
        const float* seqb = seq + (size_t)b * LL * DD;
        int wr = w >> 1, wc = w & 1;
        int fr = lane & 15, kb = lane >> 4;
        int mbase = m0 + wr * 32, nbase = n0 + wc * 32;
        f32x4 acc[2][2] = {};
        int k0c = ks * KCH;
        for (int st = 0; st < 8; ++st) {
            int kk = k0c + st * 32 + kb * 8;
            bf16x8 af[2];
            #pragma unroll
            for (int i = 0; i < 2; ++i)
                af[i] = *(const bf16x8*)(A + (size_t)(mbase + i * 16 + fr) * LL + kk);
            bf16x8 bfv[2];
            #pragma unroll
            for (int j = 0; j < 2; ++j) {
                int n = nbase + j * 16 + fr;
                const float* sp2 = seqb + (size_t)kk * DD + n;
                #pragma unroll
                for (int r = 0; r < 8; ++r)
                    bfv[j][r] = (short)f2bf(sp2[(size_t)r * DD]);
            }
            #pragma unroll
            for (int i = 0; i < 2; ++i)
                #pragma unroll
                for (int j = 0; j < 2; ++j)
                    acc[i][j] = __builtin_amdgcn_mfma_f32_16x16x32_bf16(
                        af[i], bfv[j], acc[i][j], 0, 0, 0);
        }
        unsigned short* cp =
            (unsigned short*)(ws + CPART_OFF) + (size_t)((ks * BB + b) * MM) * DD;
        #pragma unroll
        for (int i = 0; i < 2; ++i)
            #pragma unroll
            for (int j = 0; j < 2; ++j)
                #pragma unroll
                for (int r = 0; r < 4; ++r) {
                    int gm = m0 + wr * 32 + i * 16 + kb * 4 + r;
                    int gn = n0 + wc * 32 + j * 16 + fr;
                    cp[(size_t)gm * DD + gn] = f2bf(acc[i][j][r]);
                }
    } else {
        int qb = g - NGBLK;
        const unsigned short* A16 = (const unsigned short*)(ws + A16_OFF);
        #pragma unroll
        for (int i = 0; i < 8; ++i) {
            int m = qb * 32 + w * 8 + i;
            const unsigned short* rowp = A16 + (size_t)m * LL + lane * 32;
            float v = 0.f;
            #pragma unroll
            for (int u = 0; u < 4; ++u) {
                uint4 x = *(const uint4*)(rowp + u * 8);
                const unsigned short* xs = (const unsigned short*)&x;
                #pragma unroll
                for (int e = 0; e < 8; ++e) v += bf2f(xs[e]);
            }
            #pragma unroll
            for (int off = 32; off > 0; off >>= 1) v += __shfl_xor(v, off, 64);
            if (lane == 0) ws[QSUM_OFF + m] = 1.0f / v;
        }
    }
}

// ===== Kernel 4b: score GEMM; pre-scaled fp32 atomics into out / sacc =====
__global__ __launch_bounds__(256) void k4b(float* __restrict__ ws,
                                           float* __restrict__ out) {
    __shared__ __align__(16) short As[64][200];
    __shared__ __align__(16) short Bs[6][R80][40];
    int mt = blockIdx.x, sl = blockIdx.y;
    int b = mt >> 2, p0 = (mt & 3) * 64;
    int t = threadIdx.x;
    int w = t >> 6, lane = t & 63, fr = lane & 15, kb = lane >> 4;
    int row = t >> 2, sg = t & 3;
    int seg, d0, ls = 0, dgb;
    if (sl < 4)      { seg = 0; d0 = sl * 192;                              dgb = 0; }
    else if (sl < 8) { seg = 1; d0 = (sl - 4) * 192;                        dgb = DD; }
    else             { seg = 2; ls = (sl - 8) >> 2; d0 = ((sl - 8) & 3) * 192; dgb = 2 * DD; }
    int p = p0 + row, s_, o_;
    pair_so(p, s_, o_);
    int asrc = (seg == 0) ? s_ : o_;
    const unsigned short* code16 = (const unsigned short*)(ws + CODE16_OFF);
    const unsigned short* cp16 = (const unsigned short*)(ws + CPART_OFF);
    #pragma unroll
    for (int kk = 0; kk < 6; ++kk) {
        int d = d0 + kk * 32;
        if (seg < 2) {
            const float* src = ws + ENT_EMB_OFF + (size_t)(b * EE + asrc) * DD + d + sg * 8;
            cast8(*(const float4*)src, *(const float4*)(src + 4), &As[row][kk * 32 + sg * 8]);
        } else {
            *(uint4*)&As[row][kk * 32 + sg * 8] =
                *(const uint4*)(cp16 + (size_t)((ls * BB + b) * MM + p) * DD + d + sg * 8);
        }
    }
    for (int i = t; i < 6 * R80 * 4; i += 256) {
        int kk = i / (R80 * 4);
        int rem = i - kk * (R80 * 4);
        int br = rem >> 2, bsg = rem & 3;
        *(uint4*)&Bs[kk][br][bsg * 8] =
            *(const uint4*)(code16 + (size_t)br * D3 + dgb + d0 + kk * 32 + bsg * 8);
    }
    __syncthreads();
    f32x4 acc[5] = {};
    #pragma unroll
    for (int kk = 0; kk < 6; ++kk) {
        bf16x8 af = *(bf16x8*)&As[w * 16 + fr][kk * 32 + kb * 8];
        #pragma unroll
        for (int j = 0; j < 5; ++j) {
            bf16x8 bf = *(bf16x8*)&Bs[kk][j * 16 + fr][kb * 8];
            acc[j] = __builtin_amdgcn_mfma_f32_16x16x32_bf16(af, bf, acc[j], 0, 0, 0);
        }
    }
    // epilogue: pre-scale c-slices by 1/qsum, atomically fold into out / sacc
    #pragma unroll
    for (int r = 0; r < 4; ++r) {
        int lp = p0 + w * 16 + kb * 4 + r;       // pair within batch (0..255)
        if (lp >= PP) continue;                   // pad pairs
        int lm = b * MM + lp;
        float qs = (seg == 2) ? ws[QSUM_OFF + lm] : 1.0f;
        #pragma unroll
        for (int j = 0; j < 5; ++j) {
            int lr = j * 16 + fr;
            float v = acc[j][r] * qs;
            if (lr < RR) {
                atomicAdd(&out[(size_t)(b * PP + lp) * (RR + 1) + 1 + lr], v);
            } else if (lr < RR + NN) {
                atomicAdd(&ws[SACC_OFF + (size_t)lm * NN + (lr - RR)], v);
            }
        }
    }
}

// ===== Kernel F: nota max from sacc =====
__global__ __launch_bounds__(128) void kF(const float* __restrict__ ws,
                                          float* __restrict__ out) {
    int half = blockIdx.x, b = blockIdx.y;
    int t = threadIdx.x;
    int p = half * 124 + t;
    if (t < 124) {
        int m = b * MM + p;
        const float* sa = ws + SACC_OFF + (size_t)m * NN;
        float mx = -INFINITY;
        #pragma unroll
        for (int n = 0; n < NN; ++n) mx = fmaxf(mx, sa[n]);
        out[(size_t)(b * PP + p) * (RR + 1)] = mx;
    }
}

extern "C" void kernel_launch(void* const* d_in, const int* in_sizes, int n_in,
                              void* d_out, int out_size, void* d_ws, size_t ws_size,
                              hipStream_t stream) {
    const float* seq   = (const float*)d_in[0];
    const float* att   = (const float*)d_in[1];
    const float* rel   = (const float*)d_in[2];
    const float* nota  = (const float*)d_in[3];
    const int*   spans = (const int*)d_in[4];
    float* ws  = (float*)d_ws;
    float* out = (float*)d_out;

    kP<<<NQBLK + NEBLK + NCBLK + NZBLK, 256, 0, stream>>>(seq, att, rel, nota, spans, ws, out);
    k3_gemm<<<NGBLK + NQSB, 256, 0, stream>>>(seq, ws);
    k4b<<<dim3(8, NSL), 256, 0, stream>>>(ws, out);
    kF<<<dim3(2, BB), 128, 0, stream>>>(ws, out);
}

// Round 20
// 44.518 us; speedup vs baseline: 1.2829x; 1.2829x over previous
//
#include <hip/hip_runtime.h>
#include <hip/hip_bf16.h>
#include <math.h>

// Problem dims
#define BB 2
#define LL 2048
#define DD 768
#define D3 2304
#define HH 12
#define EE 32
#define RR 57
#define NN 20
#define PP 248
#define MM 256
#define KS 8
#define KCH (LL / KS)   // 256
#define R80 80
#define NSL 40          // score k-slices: 4 es + 4 eo + 32 c

// ws layout (float offsets)
#define ENT_EMB_OFF 0                           // f32 [B][EE][DD]
#define A16_OFF   (BB * EE * DD)                // bf16 [B][MM][LL]
#define A16_F     (BB * MM * LL / 2)
#define CPART_OFF (A16_OFF + A16_F)             // bf16 [KS][B][MM][DD]
#define CPART_F   (KS * BB * MM * DD / 2)
#define CODE16_OFF (CPART_OFF + CPART_F)        // bf16 [80][2304]
#define CODE16_F  (R80 * D3 / 2)
#define QSUM_OFF  (CODE16_OFF + CODE16_F)       // f32 [512]
#define SPART_OFF (QSUM_OFF + 512)              // f32 [512][NSL][80] (m-major)

// kP grid roles
#define NQBLK (BB * 256)
#define NEBLK (EE * BB)
#define NCBLK 8
#define ASTRIDE 388

// k3 grid roles
#define NGBLK 768
#define NQSB 16

typedef __attribute__((ext_vector_type(8))) short bf16x8;
typedef __attribute__((ext_vector_type(4))) float f32x4;

__device__ __forceinline__ unsigned short f2bf(float f) {
    __hip_bfloat16 h = __float2bfloat16(f);
    return __builtin_bit_cast(unsigned short, h);
}
__device__ __forceinline__ float bf2f(unsigned short u) {
    unsigned int x = ((unsigned int)u) << 16;
    return __builtin_bit_cast(float, x);
}
__device__ __forceinline__ void pair_so(int p, int& s, int& o) {
    s = p / 31;
    int r = p - s * 31;
    o = (r < s) ? r : r + 1;
}
__device__ __forceinline__ float dot4(float4 a, float4 b) {
    return a.x * b.x + a.y * b.y + a.z * b.z + a.w * b.w;
}
__device__ __forceinline__ void cast8(float4 u0, float4 u1, short* dst) {
    ushort4 a = make_ushort4(f2bf(u0.x), f2bf(u0.y), f2bf(u0.z), f2bf(u0.w));
    ushort4 b = make_ushort4(f2bf(u1.x), f2bf(u1.y), f2bf(u1.z), f2bf(u1.w));
    *(ushort4*)dst = a;
    *(ushort4*)(dst + 4) = b;
}

// ===== Kernel P: role Q (att gather, r16-proven), role E, role C =====
__global__ __launch_bounds__(256) void kP(const float* __restrict__ seq,
                                          const float* __restrict__ att,
                                          const float* __restrict__ rel,
                                          const float* __restrict__ nota,
                                          const int* __restrict__ spans,
                                          float* __restrict__ ws) {
    __shared__ __align__(16) float att_s[8][ASTRIDE];
    __shared__ int sp_s[EE];
    int bid = blockIdx.x;
    int t = threadIdx.x;

    if (bid < NQBLK) {
        int xcd = bid & 7, i = bid >> 3;
        int chunk = xcd * (NQBLK / 8) + i;       // 0..511
        int b = chunk >> 8, l0 = (chunk & 255) * 8;
        if (t < EE) sp_s[t] = spans[b * EE + t];
        __syncthreads();
        for (int i2 = t; i2 < EE * HH * 2; i2 += 256) {
            int seg = i2 & 1, eh = i2 >> 1;
            int e = eh / HH, h = eh - e * HH;
            const float* base = att + ((size_t)(b * HH + h) * LL + sp_s[e]) * LL + l0 + seg * 4;
            float4 v0 = *(const float4*)base;
            float4 v1 = *(const float4*)(base + LL);
            float4 v2 = *(const float4*)(base + 2 * LL);
            float4 v3 = *(const float4*)(base + 3 * LL);
            att_s[seg * 4 + 0][eh] = 0.25f * (v0.x + v1.x + v2.x + v3.x);
            att_s[seg * 4 + 1][eh] = 0.25f * (v0.y + v1.y + v2.y + v3.y);
            att_s[seg * 4 + 2][eh] = 0.25f * (v0.z + v1.z + v2.z + v3.z);
            att_s[seg * 4 + 3][eh] = 0.25f * (v0.w + v1.w + v2.w + v3.w);
        }
        __syncthreads();
        int p = t, s, o;
        pair_so(p, s, o);          // pads p>=248 -> s=8, o<=7: valid indices
        float q[8];
        #pragma unroll
        for (int l = 0; l < 8; ++l) {
            float4 a0 = *(const float4*)&att_s[l][s * HH];
            float4 a1 = *(const float4*)&att_s[l][s * HH + 4];
            float4 a2 = *(const float4*)&att_s[l][s * HH + 8];
            float4 b0 = *(const float4*)&att_s[l][o * HH];
            float4 b1 = *(const float4*)&att_s[l][o * HH + 4];
            float4 b2 = *(const float4*)&att_s[l][o * HH + 8];
            q[l] = dot4(a0, b0) + dot4(a1, b1) + dot4(a2, b2);
        }
        unsigned short* A16 = (unsigned short*)(ws + A16_OFF) + (size_t)(b * MM + p) * LL + l0;
        #pragma unroll
        for (int i2 = 0; i2 < 2; ++i2) {
            ushort4 ov = make_ushort4(f2bf(q[i2 * 4 + 0]), f2bf(q[i2 * 4 + 1]),
                                      f2bf(q[i2 * 4 + 2]), f2bf(q[i2 * 4 + 3]));
            *(ushort4*)(A16 + i2 * 4) = ov;
        }
    } else if (bid < NQBLK + NEBLK) {
        int bx = bid - NQBLK;
        int e = bx & 31, b = bx >> 5;
        int st = spans[b * EE + e];
        float* ee = ws + ENT_EMB_OFF + (size_t)(b * EE + e) * DD;
        const float* srow = seq + (size_t)(b * LL + st) * DD;
        for (int d = t; d < DD; d += 256) {
            ee[d] = 0.25f * (srow[d] + srow[DD + d] + srow[2 * DD + d] + srow[3 * DD + d]);
        }
    } else {
        int cid = bid - NQBLK - NEBLK;
        unsigned short* code16 = (unsigned short*)(ws + CODE16_OFF);
        for (int idx = t; idx < 10 * (D3 / 4); idx += 256) {
            int rl = idx / (D3 / 4), dg = idx - rl * (D3 / 4);
            int r = cid * 10 + rl;
            ushort4 ov;
            if (r < RR) {
                float4 v = *(const float4*)(rel + (size_t)r * D3 + dg * 4);
                ov = make_ushort4(f2bf(v.x), f2bf(v.y), f2bf(v.z), f2bf(v.w));
            } else if (r < RR + NN) {
                float4 v = *(const float4*)(nota + (size_t)(r - RR) * D3 + dg * 4);
                ov = make_ushort4(f2bf(v.x), f2bf(v.y), f2bf(v.z), f2bf(v.w));
            } else {
                ov = make_ushort4(0, 0, 0, 0);
            }
            *(ushort4*)(code16 + (size_t)r * D3 + dg * 4) = ov;
        }
    }
}

// ===== Kernel 3: [0,768) register-direct context GEMM (r18-proven, no LDS);
//                 [768,784) qsum =====
__global__ __launch_bounds__(256) void k3_gemm(const float* __restrict__ seq,
                                               float* __restrict__ ws) {
    int g = blockIdx.x;
    int t = threadIdx.x;
    int w = t >> 6, lane = t & 63;

    if (g < NGBLK) {
        int m0 = (g & 3) * 64;
        int n0 = ((g >> 2) % 12) * 64;
        int z = g / 48;
        int ks = z & 7, b = z >> 3;
        const unsigned short* A = (const unsigned short*)(ws + A16_OFF) + (size_t)b * MM * LL;
        const float* seqb = seq + (size_t)b * LL * DD;
        int wr = w >> 1, wc = w & 1;
        int fr = lane & 15, kb = lane >> 4;
        int mbase = m0 + wr * 32, nbase = n0 + wc * 32;
        f32x4 acc[2][2] = {};
        int k0c = ks * KCH;
        for (int st = 0; st < 8; ++st) {
            int kk = k0c + st * 32 + kb * 8;
            bf16x8 af[2];
            #pragma unroll
            for (int i = 0; i < 2; ++i)
                af[i] = *(const bf16x8*)(A + (size_t)(mbase + i * 16 + fr) * LL + kk);
            bf16x8 bfv[2];
            #pragma unroll
            for (int j = 0; j < 2; ++j) {
                int n = nbase + j * 16 + fr;
                const float* sp2 = seqb + (size_t)kk * DD + n;
                #pragma unroll
                for (int r = 0; r < 8; ++r)
                    bfv[j][r] = (short)f2bf(sp2[(size_t)r * DD]);
            }
            #pragma unroll
            for (int i = 0; i < 2; ++i)
                #pragma unroll
                for (int j = 0; j < 2; ++j)
                    acc[i][j] = __builtin_amdgcn_mfma_f32_16x16x32_bf16(
                        af[i], bfv[j], acc[i][j], 0, 0, 0);
        }
        unsigned short* cp =
            (unsigned short*)(ws + CPART_OFF) + (size_t)((ks * BB + b) * MM) * DD;
        #pragma unroll
        for (int i = 0; i < 2; ++i)
            #pragma unroll
            for (int j = 0; j < 2; ++j)
                #pragma unroll
                for (int r = 0; r < 4; ++r) {
                    int gm = m0 + wr * 32 + i * 16 + kb * 4 + r;
                    int gn = n0 + wc * 32 + j * 16 + fr;
                    cp[(size_t)gm * DD + gn] = f2bf(acc[i][j][r]);
                }
    } else {
        int qb = g - NGBLK;
        const unsigned short* A16 = (const unsigned short*)(ws + A16_OFF);
        #pragma unroll
        for (int i = 0; i < 8; ++i) {
            int m = qb * 32 + w * 8 + i;
            const unsigned short* rowp = A16 + (size_t)m * LL + lane * 32;
            float v = 0.f;
            #pragma unroll
            for (int u = 0; u < 4; ++u) {
                uint4 x = *(const uint4*)(rowp + u * 8);
                const unsigned short* xs = (const unsigned short*)&x;
                #pragma unroll
                for (int e = 0; e < 8; ++e) v += bf2f(xs[e]);
            }
            #pragma unroll
            for (int off = 32; off > 0; off >>= 1) v += __shfl_xor(v, off, 64);
            if (lane == 0) ws[QSUM_OFF + m] = 1.0f / v;
        }
    }
}

// ===== Kernel 4b: score GEMM, single-barrier full-LDS staging (r16-proven) =====
__global__ __launch_bounds__(256) void k4b(float* __restrict__ ws) {
    __shared__ __align__(16) short As[64][200];
    __shared__ __align__(16) short Bs[6][R80][40];
    int mt = blockIdx.x, sl = blockIdx.y;
    int b = mt >> 2, p0 = (mt & 3) * 64;
    int t = threadIdx.x;
    int w = t >> 6, lane = t & 63, fr = lane & 15, kb = lane >> 4;
    int row = t >> 2, sg = t & 3;
    int seg, d0, ls = 0, dgb;
    if (sl < 4)      { seg = 0; d0 = sl * 192;                              dgb = 0; }
    else if (sl < 8) { seg = 1; d0 = (sl - 4) * 192;                        dgb = DD; }
    else             { seg = 2; ls = (sl - 8) >> 2; d0 = ((sl - 8) & 3) * 192; dgb = 2 * DD; }
    int p = p0 + row, s_, o_;
    pair_so(p, s_, o_);
    int asrc = (seg == 0) ? s_ : o_;
    const unsigned short* code16 = (const unsigned short*)(ws + CODE16_OFF);
    const unsigned short* cp16 = (const unsigned short*)(ws + CPART_OFF);
    #pragma unroll
    for (int kk = 0; kk < 6; ++kk) {
        int d = d0 + kk * 32;
        if (seg < 2) {
            const float* src = ws + ENT_EMB_OFF + (size_t)(b * EE + asrc) * DD + d + sg * 8;
            cast8(*(const float4*)src, *(const float4*)(src + 4), &As[row][kk * 32 + sg * 8]);
        } else {
            *(uint4*)&As[row][kk * 32 + sg * 8] =
                *(const uint4*)(cp16 + (size_t)((ls * BB + b) * MM + p) * DD + d + sg * 8);
        }
    }
    for (int i = t; i < 6 * R80 * 4; i += 256) {
        int kk = i / (R80 * 4);
        int rem = i - kk * (R80 * 4);
        int br = rem >> 2, bsg = rem & 3;
        *(uint4*)&Bs[kk][br][bsg * 8] =
            *(const uint4*)(code16 + (size_t)br * D3 + dgb + d0 + kk * 32 + bsg * 8);
    }
    __syncthreads();
    f32x4 acc[5] = {};
    #pragma unroll
    for (int kk = 0; kk < 6; ++kk) {
        bf16x8 af = *(bf16x8*)&As[w * 16 + fr][kk * 32 + kb * 8];
        #pragma unroll
        for (int j = 0; j < 5; ++j) {
            bf16x8 bf = *(bf16x8*)&Bs[kk][j * 16 + fr][kb * 8];
            acc[j] = __builtin_amdgcn_mfma_f32_16x16x32_bf16(af, bf, acc[j], 0, 0, 0);
        }
    }
    // spart layout: [m 512][sl 40][r 80]
    float* sp = ws + SPART_OFF;
    #pragma unroll
    for (int j = 0; j < 5; ++j)
        #pragma unroll
        for (int r = 0; r < 4; ++r) {
            int lm = mt * 64 + w * 16 + kb * 4 + r;
            int lr = j * 16 + fr;
            sp[((size_t)lm * NSL + sl) * R80 + lr] = acc[j][r];
        }
}

// ===== Kernel F: reduce 40 slices (m-major), qsum on c, nota max (r16-proven) =====
__global__ __launch_bounds__(256) void kF(const float* __restrict__ ws,
                                          float* __restrict__ out) {
    __shared__ float nota_s[2][NN];
    int pt2 = blockIdx.x, b = blockIdx.y;
    int t = threadIdx.x;
    if (t < 2 * 77) {
        int j = (t < 77) ? 0 : 1;
        int r = (t < 77) ? t : t - 77;
        int p = pt2 * 2 + j;
        int m = b * MM + p;
        const float* sp = ws + SPART_OFF + (size_t)m * NSL * R80 + r;
        float raw = 0.f, csum = 0.f;
        #pragma unroll
        for (int sl = 0; sl < 8; ++sl) raw += sp[(size_t)sl * R80];
        #pragma unroll
        for (int sl = 8; sl < NSL; ++sl) csum += sp[(size_t)sl * R80];
        float v = raw + ws[QSUM_OFF + m] * csum;
        if (r < RR) out[(size_t)(b * PP + p) * (RR + 1) + 1 + r] = v;
        else nota_s[j][r - RR] = v;
    }
    __syncthreads();
    if (t < 2) {
        float mx = -INFINITY;
        #pragma unroll
        for (int n = 0; n < NN; ++n) mx = fmaxf(mx, nota_s[t][n]);
        out[(size_t)(b * PP + pt2 * 2 + t) * (RR + 1)] = mx;
    }
}

extern "C" void kernel_launch(void* const* d_in, const int* in_sizes, int n_in,
                              void* d_out, int out_size, void* d_ws, size_t ws_size,
                              hipStream_t stream) {
    const float* seq   = (const float*)d_in[0];
    const float* att   = (const float*)d_in[1];
    const float* rel   = (const float*)d_in[2];
    const float* nota  = (const float*)d_in[3];
    const int*   spans = (const int*)d_in[4];
    float* ws  = (float*)d_ws;
    float* out = (float*)d_out;

    kP<<<NQBLK + NEBLK + NCBLK, 256, 0, stream>>>(seq, att, rel, nota, spans, ws);
    k3_gemm<<<NGBLK + NQSB, 256, 0, stream>>>(seq, ws);
    k4b<<<dim3(8, NSL), 256, 0, stream>>>(ws);
    kF<<<dim3(PP / 2, BB), 256, 0, stream>>>(ws, out);
}

// Round 21
// 43.371 us; speedup vs baseline: 1.3168x; 1.0264x over previous
//
#include <hip/hip_runtime.h>
#include <hip/hip_bf16.h>
#include <math.h>

// Problem dims
#define BB 2
#define LL 2048
#define DD 768
#define D3 2304
#define HH 12
#define EE 32
#define RR 57
#define NN 20
#define PP 248
#define MM 256          // P padded to 256
#define KS 8            // K-split in context GEMM
#define KCH (LL / KS)   // 256
#define R80 80          // 77 code rows padded to 80
#define NSL 40          // score k-slices: 4 es + 4 eo + 32 c (8 ls x 4 dchunk)

// ws layout (float offsets)
#define ENT_EMB_OFF 0                           // f32 [B][EE][DD]
#define A16_OFF   (BB * EE * DD)                // bf16 [B][MM][LL]
#define A16_F     (BB * MM * LL / 2)
#define CPART_OFF (A16_OFF + A16_F)             // bf16 [KS][B][MM][DD]
#define CPART_F   (KS * BB * MM * DD / 2)
#define CODE16_OFF (CPART_OFF + CPART_F)        // bf16 [80][2304]
#define CODE16_F  (R80 * D3 / 2)
#define QSUM_OFF  (CODE16_OFF + CODE16_F)       // f32 [512] (1/qsum)
#define SPART_OFF (QSUM_OFF + 512)              // f32 [NSL][512][80]

// kP grid roles
#define NQBLK (BB * 256)          // 512 q blocks (8-l chunks), XCD-swizzled
#define NEBLK (EE * BB)           // 64 ent_emb blocks
#define NCBLK 8                   // code-cast blocks
#define ASTRIDE 388               // att_s row stride (floats)

// k3 grid roles (1D)
#define NGBLK 768                 // GEMM blocks
#define NQSB 16                   // qsum blocks (32 pairs each)

typedef __attribute__((ext_vector_type(8))) short bf16x8;
typedef __attribute__((ext_vector_type(4))) float f32x4;

__device__ __forceinline__ unsigned short f2bf(float f) {
    __hip_bfloat16 h = __float2bfloat16(f);
    return __builtin_bit_cast(unsigned short, h);
}
__device__ __forceinline__ float bf2f(unsigned short u) {
    unsigned int x = ((unsigned int)u) << 16;
    return __builtin_bit_cast(float, x);
}
__device__ __forceinline__ void pair_so(int p, int& s, int& o) {
    s = p / 31;
    int r = p - s * 31;
    o = (r < s) ? r : r + 1;
}
__device__ __forceinline__ float dot4(float4 a, float4 b) {
    return a.x * b.x + a.y * b.y + a.z * b.z + a.w * b.w;
}
__device__ __forceinline__ void cast8(float4 u0, float4 u1, short* dst) {
    ushort4 a = make_ushort4(f2bf(u0.x), f2bf(u0.y), f2bf(u0.z), f2bf(u0.w));
    ushort4 b = make_ushort4(f2bf(u1.x), f2bf(u1.y), f2bf(u1.z), f2bf(u1.w));
    *(ushort4*)dst = a;
    *(ushort4*)(dst + 4) = b;
}

// ===== Kernel P: role Q (att gather, 8-l chunks, XCD-swizzled), role E, role C =====
__global__ __launch_bounds__(256) void kP(const float* __restrict__ seq,
                                          const float* __restrict__ att,
                                          const float* __restrict__ rel,
                                          const float* __restrict__ nota,
                                          const int* __restrict__ spans,
                                          float* __restrict__ ws) {
    __shared__ __align__(16) float att_s[8][ASTRIDE];
    __shared__ int sp_s[EE];
    int bid = blockIdx.x;
    int t = threadIdx.x;

    if (bid < NQBLK) {
        int xcd = bid & 7, i = bid >> 3;
        int chunk = xcd * (NQBLK / 8) + i;       // 0..511
        int b = chunk >> 8, l0 = (chunk & 255) * 8;
        if (t < EE) sp_s[t] = spans[b * EE + t];
        __syncthreads();
        for (int i2 = t; i2 < EE * HH * 2; i2 += 256) {
            int seg = i2 & 1, eh = i2 >> 1;
            int e = eh / HH, h = eh - e * HH;
            const float* base = att + ((size_t)(b * HH + h) * LL + sp_s[e]) * LL + l0 + seg * 4;
            float4 v0 = *(const float4*)base;
            float4 v1 = *(const float4*)(base + LL);
            float4 v2 = *(const float4*)(base + 2 * LL);
            float4 v3 = *(const float4*)(base + 3 * LL);
            att_s[seg * 4 + 0][eh] = 0.25f * (v0.x + v1.x + v2.x + v3.x);
            att_s[seg * 4 + 1][eh] = 0.25f * (v0.y + v1.y + v2.y + v3.y);
            att_s[seg * 4 + 2][eh] = 0.25f * (v0.z + v1.z + v2.z + v3.z);
            att_s[seg * 4 + 3][eh] = 0.25f * (v0.w + v1.w + v2.w + v3.w);
        }
        __syncthreads();
        int p = t, s, o;
        pair_so(p, s, o);          // pads p>=248 -> s=8, o<=7: valid indices
        float q[8];
        #pragma unroll
        for (int l = 0; l < 8; ++l) {
            float4 a0 = *(const float4*)&att_s[l][s * HH];
            float4 a1 = *(const float4*)&att_s[l][s * HH + 4];
            float4 a2 = *(const float4*)&att_s[l][s * HH + 8];
            float4 b0 = *(const float4*)&att_s[l][o * HH];
            float4 b1 = *(const float4*)&att_s[l][o * HH + 4];
            float4 b2 = *(const float4*)&att_s[l][o * HH + 8];
            q[l] = dot4(a0, b0) + dot4(a1, b1) + dot4(a2, b2);
        }
        unsigned short* A16 = (unsigned short*)(ws + A16_OFF) + (size_t)(b * MM + p) * LL + l0;
        #pragma unroll
        for (int i2 = 0; i2 < 2; ++i2) {
            ushort4 ov = make_ushort4(f2bf(q[i2 * 4 + 0]), f2bf(q[i2 * 4 + 1]),
                                      f2bf(q[i2 * 4 + 2]), f2bf(q[i2 * 4 + 3]));
            *(ushort4*)(A16 + i2 * 4) = ov;
        }
    } else if (bid < NQBLK + NEBLK) {
        int bx = bid - NQBLK;
        int e = bx & 31, b = bx >> 5;
        int st = spans[b * EE + e];
        float* ee = ws + ENT_EMB_OFF + (size_t)(b * EE + e) * DD;
        const float* srow = seq + (size_t)(b * LL + st) * DD;
        for (int d = t; d < DD; d += 256) {
            ee[d] = 0.25f * (srow[d] + srow[DD + d] + srow[2 * DD + d] + srow[3 * DD + d]);
        }
    } else {
        // role C: cast code rows (rel 0..56, nota 57..76, zeros 77..79) -> bf16
        int cid = bid - NQBLK - NEBLK;          // 0..7, 10 rows each
        unsigned short* code16 = (unsigned short*)(ws + CODE16_OFF);
        for (int idx = t; idx < 10 * (D3 / 4); idx += 256) {
            int rl = idx / (D3 / 4), dg = idx - rl * (D3 / 4);
            int r = cid * 10 + rl;
            ushort4 ov;
            if (r < RR) {
                float4 v = *(const float4*)(rel + (size_t)r * D3 + dg * 4);
                ov = make_ushort4(f2bf(v.x), f2bf(v.y), f2bf(v.z), f2bf(v.w));
            } else if (r < RR + NN) {
                float4 v = *(const float4*)(nota + (size_t)(r - RR) * D3 + dg * 4);
                ov = make_ushort4(f2bf(v.x), f2bf(v.y), f2bf(v.z), f2bf(v.w));
            } else {
                ov = make_ushort4(0, 0, 0, 0);
            }
            *(ushort4*)(code16 + (size_t)r * D3 + dg * 4) = ov;
        }
    }
}

// ===== Kernel 3 (1D grid): [0,768) context GEMM -> bf16 cpart; [768,784) qsum =====
__global__ __launch_bounds__(256) void k3_gemm(const float* __restrict__ seq,
                                               float* __restrict__ ws) {
    __shared__ __align__(16) short As[64][40];
    __shared__ __align__(16) short Bs[64][40];
    int g = blockIdx.x;
    int t = threadIdx.x;
    int w = t >> 6, lane = t & 63;

    if (g < NGBLK) {
        int m0 = (g & 3) * 64;
        int n0 = ((g >> 2) % 12) * 64;
        int z = g / 48;
        int ks = z & 7, b = z >> 3;
        const unsigned short* A = (const unsigned short*)(ws + A16_OFF) + (size_t)b * MM * LL;
        int row = t >> 2, seg = t & 3;
        int bl = t >> 3, bd = t & 7;
        int wr = w >> 1, wc = w & 1;
        int fr = lane & 15, kb = lane >> 4;
        f32x4 acc[2][2] = {};
        int k0c = ks * KCH;
        for (int st = 0; st < KCH / 32; ++st) {
            int kk = k0c + st * 32;
            *(uint4*)&As[row][seg * 8] = *(const uint4*)(A + (size_t)(m0 + row) * LL + kk + seg * 8);
            {
                const float* sp2 = seq + (size_t)(b * LL + kk + bl) * DD + n0 + bd * 8;
                float4 u0 = *(const float4*)sp2;
                float4 u1 = *(const float4*)(sp2 + 4);
                unsigned short bv[8] = {f2bf(u0.x), f2bf(u0.y), f2bf(u0.z), f2bf(u0.w),
                                        f2bf(u1.x), f2bf(u1.y), f2bf(u1.z), f2bf(u1.w)};
                #pragma unroll
                for (int i = 0; i < 8; ++i) {
                    int k = (i + bd) & 7;
                    Bs[bd * 8 + k][bl] = (short)bv[k];
                }
            }
            __syncthreads();
            bf16x8 af[2], bfr[2];
            #pragma unroll
            for (int i = 0; i < 2; ++i) af[i] = *(bf16x8*)&As[wr * 32 + i * 16 + fr][kb * 8];
            #pragma unroll
            for (int j = 0; j < 2; ++j) bfr[j] = *(bf16x8*)&Bs[wc * 32 + j * 16 + fr][kb * 8];
            #pragma unroll
            for (int i = 0; i < 2; ++i)
                #pragma unroll
                for (int j = 0; j < 2; ++j)
                    acc[i][j] = __builtin_amdgcn_mfma_f32_16x16x32_bf16(
                        af[i], bfr[j], acc[i][j], 0, 0, 0);
            __syncthreads();
        }
        unsigned short* cp =
            (unsigned short*)(ws + CPART_OFF) + (size_t)((ks * BB + b) * MM) * DD;
        #pragma unroll
        for (int i = 0; i < 2; ++i)
            #pragma unroll
            for (int j = 0; j < 2; ++j)
                #pragma unroll
                for (int r = 0; r < 4; ++r) {
                    int gm = m0 + wr * 32 + i * 16 + kb * 4 + r;
                    int gn = n0 + wc * 32 + j * 16 + fr;
                    cp[(size_t)gm * DD + gn] = f2bf(acc[i][j][r]);
                }
    } else {
        // qsum role: 32 pair-rows per block, 8 per wave
        int qb = g - NGBLK;
        const unsigned short* A16 = (const unsigned short*)(ws + A16_OFF);
        #pragma unroll
        for (int i = 0; i < 8; ++i) {
            int m = qb * 32 + w * 8 + i;
            const unsigned short* rowp = A16 + (size_t)m * LL + lane * 32;
            float v = 0.f;
            #pragma unroll
            for (int u = 0; u < 4; ++u) {
                uint4 x = *(const uint4*)(rowp + u * 8);
                const unsigned short* xs = (const unsigned short*)&x;
                #pragma unroll
                for (int e = 0; e < 8; ++e) v += bf2f(xs[e]);
            }
            #pragma unroll
            for (int off = 32; off > 0; off >>= 1) v += __shfl_xor(v, off, 64);
            if (lane == 0) ws[QSUM_OFF + m] = 1.0f / v;
        }
    }
}

// ===== Kernel 4b: score GEMM. grid (8 mtiles, 40 kslices). A gathered on the fly. =====
__global__ __launch_bounds__(256) void k4b(float* __restrict__ ws) {
    __shared__ __align__(16) short As[64][40];
    __shared__ __align__(16) short Bs[R80][40];
    int mt = blockIdx.x, sl = blockIdx.y;
    int b = mt >> 2, p0 = (mt & 3) * 64;
    int t = threadIdx.x;
    int w = t >> 6, lane = t & 63, fr = lane & 15, kb = lane >> 4;
    int row = t >> 2, sg = t & 3;
    int seg, d0, ls = 0, dgb;
    if (sl < 4)      { seg = 0; d0 = sl * 192;                              dgb = 0; }
    else if (sl < 8) { seg = 1; d0 = (sl - 4) * 192;                        dgb = DD; }
    else             { seg = 2; ls = (sl - 8) >> 2; d0 = ((sl - 8) & 3) * 192; dgb = 2 * DD; }
    int p = p0 + row, s_, o_;
    pair_so(p, s_, o_);
    int asrc = (seg == 0) ? s_ : o_;
    const unsigned short* code16 = (const unsigned short*)(ws + CODE16_OFF);
    const unsigned short* cp16 = (const unsigned short*)(ws + CPART_OFF);
    f32x4 acc[5] = {};
    for (int kk = 0; kk < 6; ++kk) {
        int d = d0 + kk * 32;
        if (seg < 2) {
            const float* src = ws + ENT_EMB_OFF + (size_t)(b * EE + asrc) * DD + d + sg * 8;
            cast8(*(const float4*)src, *(const float4*)(src + 4), &As[row][sg * 8]);
        } else {
            *(uint4*)&As[row][sg * 8] =
                *(const uint4*)(cp16 + (size_t)((ls * BB + b) * MM + p) * DD + d + sg * 8);
        }
        for (int i = t; i < R80 * 4; i += 256) {
            int br = i >> 2, bsg = i & 3;
            *(uint4*)&Bs[br][bsg * 8] =
                *(const uint4*)(code16 + (size_t)br * D3 + dgb + d + bsg * 8);
        }
        __syncthreads();
        bf16x8 af = *(bf16x8*)&As[w * 16 + fr][kb * 8];
        #pragma unroll
        for (int j = 0; j < 5; ++j) {
            bf16x8 bf = *(bf16x8*)&Bs[j * 16 + fr][kb * 8];
            acc[j] = __builtin_amdgcn_mfma_f32_16x16x32_bf16(af, bf, acc[j], 0, 0, 0);
        }
        __syncthreads();
    }
    float* sp = ws + SPART_OFF + (size_t)sl * 512 * R80 + (size_t)(mt * 64) * R80;
    #pragma unroll
    for (int j = 0; j < 5; ++j)
        #pragma unroll
        for (int r = 0; r < 4; ++r) {
            int lm = w * 16 + kb * 4 + r;
            int lr = j * 16 + fr;
            sp[(size_t)lm * R80 + lr] = acc[j][r];
        }
}

// ===== Kernel F: reduce 40 slices, apply 1/qsum to c-slices, nota max =====
__global__ __launch_bounds__(256) void kF(const float* __restrict__ ws,
                                          float* __restrict__ out) {
    __shared__ float nota_s[2][NN];
    int pt2 = blockIdx.x, b = blockIdx.y;
    int t = threadIdx.x;
    if (t < 2 * 77) {
        int j = (t < 77) ? 0 : 1;
        int r = (t < 77) ? t : t - 77;
        int p = pt2 * 2 + j;
        int m = b * MM + p;
        const float* sp = ws + SPART_OFF + (size_t)m * R80 + r;
        float raw = 0.f, csum = 0.f;
        #pragma unroll
        for (int sl = 0; sl < 8; ++sl) raw += sp[(size_t)sl * 512 * R80];
        #pragma unroll
        for (int sl = 8; sl < NSL; ++sl) csum += sp[(size_t)sl * 512 * R80];
        float v = raw + ws[QSUM_OFF + m] * csum;
        if (r < RR) out[(size_t)(b * PP + p) * (RR + 1) + 1 + r] = v;
        else nota_s[j][r - RR] = v;
    }
    __syncthreads();
    if (t < 2) {
        float mx = -INFINITY;
        #pragma unroll
        for (int n = 0; n < NN; ++n) mx = fmaxf(mx, nota_s[t][n]);
        out[(size_t)(b * PP + pt2 * 2 + t) * (RR + 1)] = mx;
    }
}

extern "C" void kernel_launch(void* const* d_in, const int* in_sizes, int n_in,
                              void* d_out, int out_size, void* d_ws, size_t ws_size,
                              hipStream_t stream) {
    const float* seq   = (const float*)d_in[0];
    const float* att   = (const float*)d_in[1];
    const float* rel   = (const float*)d_in[2];
    const float* nota  = (const float*)d_in[3];
    const int*   spans = (const int*)d_in[4];
    float* ws  = (float*)d_ws;
    float* out = (float*)d_out;

    kP<<<NQBLK + NEBLK + NCBLK, 256, 0, stream>>>(seq, att, rel, nota, spans, ws);
    k3_gemm<<<NGBLK + NQSB, 256, 0, stream>>>(seq, ws);
    k4b<<<dim3(8, NSL), 256, 0, stream>>>(ws);
    kF<<<dim3(PP / 2, BB), 256, 0, stream>>>(ws, out);
}